// Round 2
// baseline (206.613 us; speedup 1.0000x reference)
//
#include <hip/hip_runtime.h>

// YOLO v1 loss, B=16384, S=7, C=30. Memory-bound reduction: 192.7 MB read -> 1 float.
// Layout: pred[((b*S+i)*S+j)*30 + c]; i -> gi (x offset), j -> gj (y offset).
//
// v2 (resubmit after infra flake): LDS-staged coalesced loads. The 120B/cell
// record defeats per-thread coalescing (30 scattered dwordx2/thread =
// transaction-bound at ~1.3 TB/s). Each 256-thread block stages its 256 cells
// (30720 B) via dense float4 loads (15/thread, minimal-transaction), single LDS
// buffer reused pred->targ to keep LDS at 120 B/thread (5 blocks/CU, 20 waves/CU).

#define NS 7
#define NC 30
#define BLOCK 256
#define F4_PER_BLOCK (BLOCK * NC / 4)  // 1920 float4 = 30720 B

__global__ void zero_out_kernel(float* out) { out[0] = 0.0f; }

__global__ __launch_bounds__(BLOCK) void yolo_loss_kernel(
    const float* __restrict__ pred,
    const float* __restrict__ targ,
    float* __restrict__ out,
    int n_cells, float inv_B)
{
    const float STEP = 1.0f / 7.0f;
    const float L_COORD = 5.0f;
    const float L_NOOBJ = 0.5f;

    __shared__ float4 sbuf4[F4_PER_BLOCK];
    float* sbuf = (float*)sbuf4;

    const int tid = threadIdx.x;
    const int cell = blockIdx.x * BLOCK + tid;
    // n_cells = 802816 = 3136 * 256 exactly: every block is full, staging needs no guard.

    const float4* pg = (const float4*)pred + (size_t)blockIdx.x * F4_PER_BLOCK;
    const float4* tg = (const float4*)targ + (size_t)blockIdx.x * F4_PER_BLOCK;

    // ---- stage pred (dense, coalesced float4: 7.5 iters of 256 lanes) ----
    #pragma unroll
    for (int k = 0; k < 7; ++k) sbuf4[tid + k * BLOCK] = pg[tid + k * BLOCK];
    if (tid < F4_PER_BLOCK - 7 * BLOCK) sbuf4[tid + 7 * BLOCK] = pg[tid + 7 * BLOCK];
    __syncthreads();

    // ---- own cell's 30 pred floats -> registers (static indices only) ----
    float p[NC];
    {
        const float2* s2 = (const float2*)sbuf + tid * (NC / 2);
        #pragma unroll
        for (int k = 0; k < NC / 2; ++k) {
            float2 v = s2[k];
            p[2 * k] = v.x;
            p[2 * k + 1] = v.y;
        }
    }
    __syncthreads();  // all p reads done before overwrite

    // ---- stage targ into the same buffer ----
    #pragma unroll
    for (int k = 0; k < 7; ++k) sbuf4[tid + k * BLOCK] = tg[tid + k * BLOCK];
    if (tid < F4_PER_BLOCK - 7 * BLOCK) sbuf4[tid + 7 * BLOCK] = tg[tid + 7 * BLOCK];
    __syncthreads();

    float lsum = 0.0f;
    if (cell < n_cells) {
        int j = cell % NS;            // second spatial axis -> gj
        int i = (cell / NS) % NS;     // first spatial axis  -> gi
        float gi = (float)i;
        float gj = (float)j;

        const float2* s2 = (const float2*)sbuf + tid * (NC / 2);
        float2 t01 = s2[0];           // t[0], t[1]
        float2 t23 = s2[1];           // t[2], t[3]
        float2 t45 = s2[2];           // t[4], (t[5] unused)
        float2 t89 = s2[4];           // (t[8] unused), t[9]
        float t0 = t01.x, t1 = t01.y, t2 = t23.x, t3 = t23.y;
        float t4 = t45.x, t9 = t89.y;

        // _convert_box for target, pred box1 (ch 0:4), pred box2 (ch 5:9)
        float ta, tb, tc, td;
        {
            float cx = (t0 + gi) * STEP;
            float cy = (t1 + gj) * STEP;
            ta = fmaxf(cx - t2 * 0.5f, 0.0f);
            tb = fmaxf(cy - t3 * 0.5f, 0.0f);
            tc = fminf(cx + t2 * 0.5f, 1.0f);
            td = fminf(cy + t3 * 0.5f, 1.0f);
        }
        float q1, w1, e1, r1;
        {
            float cx = (p[0] + gi) * STEP;
            float cy = (p[1] + gj) * STEP;
            q1 = fmaxf(cx - p[2] * 0.5f, 0.0f);
            w1 = fmaxf(cy - p[3] * 0.5f, 0.0f);
            e1 = fminf(cx + p[2] * 0.5f, 1.0f);
            r1 = fminf(cy + p[3] * 0.5f, 1.0f);
        }
        float q2, w2, e2, r2;
        {
            float cx = (p[5] + gi) * STEP;
            float cy = (p[6] + gj) * STEP;
            q2 = fmaxf(cx - p[7] * 0.5f, 0.0f);
            w2 = fmaxf(cy - p[8] * 0.5f, 0.0f);
            e2 = fminf(cx + p[7] * 0.5f, 1.0f);
            r2 = fminf(cy + p[8] * 0.5f, 1.0f);
        }

        float tarea = (td - tb) * (tc - ta);
        // _iou(tbox, pbox): inter NOT clamped; iou = inter>0 ? inter/(union+1e-5) : 0
        float iou1, iou2;
        {
            float minx = fmaxf(ta, q1), miny = fmaxf(tb, w1);
            float maxx = fminf(tc, e1), maxy = fminf(td, r1);
            float inter = (maxy - miny) * (maxx - minx);
            float uni = (e1 - q1) * (r1 - w1) + tarea - inter;
            iou1 = (inter > 0.0f) ? inter / (uni + 1e-5f) : 0.0f;
        }
        {
            float minx = fmaxf(ta, q2), miny = fmaxf(tb, w2);
            float maxx = fminf(tc, e2), maxy = fminf(td, r2);
            float inter = (maxy - miny) * (maxx - minx);
            float uni = (e2 - q2) * (r2 - w2) + tarea - inter;
            iou2 = (inter > 0.0f) ? inter / (uni + 1e-5f) : 0.0f;
        }

        bool sel2 = (iou1 <= iou2);
        float conf_t = sel2 ? iou2 : iou1;
        float px = sel2 ? p[5] : p[0];
        float py = sel2 ? p[6] : p[1];
        float pw = sel2 ? p[7] : p[2];
        float ph = sel2 ? p[8] : p[3];
        float pconf = sel2 ? p[9] : p[4];

        float obj = (t4 > 0.0f) ? 1.0f : 0.0f;
        float noobj = (t4 == 0.0f) ? 1.0f : 0.0f;

        float dx = px - t0, dy = py - t1;
        float dw = pw - t2, dh = ph - t3;
        float coord = dx * dx + dy * dy + dw * dw + dh * dh;

        float dc = pconf - conf_t;
        float obj_loss = dc * dc;

        float cls = 0.0f;
        #pragma unroll
        for (int k = 0; k < 10; ++k) {
            float2 tv = s2[5 + k];    // t[10+2k], t[11+2k]
            float d0 = p[10 + 2 * k] - tv.x;
            float d1 = p[11 + 2 * k] - tv.y;
            cls += d0 * d0;
            cls += d1 * d1;
        }

        float d4 = p[4] - t4;
        float d9 = p[9] - t9;
        float noobj_loss = d4 * d4 + d9 * d9;

        lsum = obj * (obj_loss + L_COORD * coord + cls) + L_NOOBJ * noobj * noobj_loss;
    }

    // wave(64) shuffle reduce
    #pragma unroll
    for (int off = 32; off > 0; off >>= 1)
        lsum += __shfl_down(lsum, off, 64);

    __shared__ float wsum[4];
    int lane = threadIdx.x & 63;
    int wid = threadIdx.x >> 6;
    if (lane == 0) wsum[wid] = lsum;
    __syncthreads();
    if (threadIdx.x == 0) {
        float s = (wsum[0] + wsum[1]) + (wsum[2] + wsum[3]);
        atomicAdd(out, s * inv_B);
    }
}

extern "C" void kernel_launch(void* const* d_in, const int* in_sizes, int n_in,
                              void* d_out, int out_size, void* d_ws, size_t ws_size,
                              hipStream_t stream) {
    const float* pred = (const float*)d_in[0];
    const float* targ = (const float*)d_in[1];
    float* out = (float*)d_out;

    const int B = 16384;
    const int n_cells = B * NS * NS;  // 802816
    const float inv_B = 1.0f / (float)B;

    zero_out_kernel<<<1, 1, 0, stream>>>(out);

    const int grid = (n_cells + BLOCK - 1) / BLOCK;  // 3136 (exact: no partial blocks)
    yolo_loss_kernel<<<grid, BLOCK, 0, stream>>>(pred, targ, out, n_cells, inv_B);
}